// Round 10
// baseline (444.467 us; speedup 1.0000x reference)
//
#include <hip/hip_runtime.h>
#include <hip/hip_fp16.h>

#define N_NODES 25000
#define N_EDGES 400000
#define EPS_F 1e-5f

typedef _Float16 f16x8 __attribute__((ext_vector_type(8)));
typedef _Float16 f16x4 __attribute__((ext_vector_type(4)));
typedef float    f32x4 __attribute__((ext_vector_type(4)));
typedef unsigned int uint;

__device__ __forceinline__ float silu_f(float x) {
    return x / (1.0f + __expf(-x));
}

// ---------------------------------------------------------------------------
// K0: pre-pack Wfc1/2/3 into MFMA A-fragment order (R7/R8-verified layout).
// ---------------------------------------------------------------------------
__global__ __launch_bounds__(256) void k_prepack(
    const float* __restrict__ Wfc1, const float* __restrict__ Wfc2,
    const float* __restrict__ Wfc3,
    _Float16* __restrict__ gA1, _Float16* __restrict__ gA2,
    _Float16* __restrict__ gA3)
{
    int t = blockIdx.x * 256 + threadIdx.x;
    int L = t & 63, q = L >> 4, cc = L & 15;
    if (t < 256) {
        int nt = t >> 6;
        f16x8 p;
#pragma unroll
        for (int j = 0; j < 8; ++j)
            p[j] = (q == 0) ? (_Float16)Wfc1[j*64 + nt*16 + cc] : (_Float16)0.f;
        *(f16x8*)&gA1[t*8] = p;
    } else if (t < 768) {
        int tt = t - 256;
        int tile = tt >> 6, ks = tile >> 2, nt = tile & 3;
        int kb = ks*32 + q*8;
        f16x8 p;
#pragma unroll
        for (int j = 0; j < 8; ++j)
            p[j] = (_Float16)Wfc2[(kb+j)*64 + nt*16 + cc];
        *(f16x8*)&gA2[tt*8] = p;
    } else if (t < 2560) {
        int tt = t - 768;
        int tile = tt >> 6, ks = tile / 14, nt = tile - ks*14;
        int kb = ks*32 + q*8;
        f16x8 p;
#pragma unroll
        for (int j = 0; j < 8; ++j)
            p[j] = (_Float16)Wfc3[(kb+j)*224 + nt*16 + cc];
        *(f16x8*)&gA3[tt*8] = p;
    }
}

// ---------------------------------------------------------------------------
// K1: per-node linear transforms, WAVE-per-node (R7/R8-verified).
// XS/SC row: [0..63]=s, [64+v*4+c]=v (c<3, pad).
// ---------------------------------------------------------------------------
__global__ __launch_bounds__(256) void k_node_pre(
    const float* __restrict__ nh,
    const float* __restrict__ W1_0, const float* __restrict__ W1_1,
    const float* __restrict__ Wsc0, const float* __restrict__ Wsc1,
    float* __restrict__ XS, float* __restrict__ SC)
{
    int lane = threadIdx.x & 63, wv = threadIdx.x >> 6;
    int n = blockIdx.x*4 + wv;
    if (n >= N_NODES) return;
    int u_ = lane & 31;
    bool lo = lane < 32;
    const float* row = nh + n*160;

    float sval = row[lane];
    float vx = row[64 + u_*3 + 0];
    float vy = row[64 + u_*3 + 1];
    float vz = row[64 + u_*3 + 2];

    float as = 0.f, bs = 0.f;
#pragma unroll 4
    for (int k = 0; k < 64; ++k) {
        float sk = __shfl(sval, k);
        as += sk * W1_0[k*64 + lane];
        bs += sk * Wsc0[k*64 + lane];
    }
    float* xsrow = XS + n*192;
    float* scrow = SC + n*192;
    xsrow[lane] = as * 0.125f;
    scrow[lane] = bs * 0.125f;

    float selv = lo ? vx : vz;
    int srcbase = lane & 32;                   // hi lanes source vz from 32..63
    float aP=0.f, aQ=0.f, bP=0.f, bQ=0.f;
#pragma unroll 4
    for (int u = 0; u < 32; ++u) {
        float su = __shfl(selv, u | srcbase);
        float sy = __shfl(vy, u);
        float wa = W1_1[u*32 + u_];
        float wb = Wsc1[u*32 + u_];
        aP += su*wa; aQ += sy*wa;
        bP += su*wb; bQ += sy*wb;
    }
    const float is32 = 0.17677669529663687f;
    if (lo) {
        xsrow[64 + u_*4 + 0] = aP * is32;
        xsrow[64 + u_*4 + 1] = aQ * is32;
        scrow[64 + u_*4 + 0] = bP * is32;
        scrow[64 + u_*4 + 1] = bQ * is32;
    } else {
        xsrow[64 + u_*4 + 2] = aP * is32;
        scrow[64 + u_*4 + 2] = bP * is32;
    }
}

// ---------------------------------------------------------------------------
// K2a: per-src degree counts (int atomics only).
// ---------------------------------------------------------------------------
__global__ __launch_bounds__(256) void k_count(
    const int* __restrict__ ei, int* __restrict__ CNT)
{
    int e = blockIdx.x * 256 + threadIdx.x;
    if (e >= N_EDGES) return;
    atomicAdd(&CNT[ei[e]], 1);
}

// ---------------------------------------------------------------------------
// K2b: exclusive scan of CNT -> ROWP (single block, 256 threads: per-thread
// serial chunk sums + wave/block scan of partials + serial write-back).
// ---------------------------------------------------------------------------
__global__ __launch_bounds__(256) void k_scan(
    const int* __restrict__ CNT, int* __restrict__ ROWP)
{
    __shared__ int wsum[4];
    const int CH = (N_NODES + 255) / 256;   // 98
    int tid = threadIdx.x;
    int lane = tid & 63, wv = tid >> 6;
    int base = tid * CH;
    int s = 0;
    for (int j = 0; j < CH; ++j) {
        int idx = base + j;
        if (idx < N_NODES) s += CNT[idx];
    }
    int inc = s;
    for (int off = 1; off < 64; off <<= 1) {
        int o = __shfl_up(inc, off);
        if (lane >= off) inc += o;
    }
    if (lane == 63) wsum[wv] = inc;
    __syncthreads();
    int woff = 0;
    for (int w = 0; w < wv; ++w) woff += wsum[w];
    int run = woff + inc - s;               // exclusive prefix for this thread
    for (int j = 0; j < CH; ++j) {
        int idx = base + j;
        if (idx < N_NODES) { ROWP[idx] = run; run += CNT[idx]; }
    }
}

// ---------------------------------------------------------------------------
// K2c: assign slots (counting sort) + pre-gather sh and dst into slot order.
// ---------------------------------------------------------------------------
__global__ __launch_bounds__(256) void k_fill(
    const int* __restrict__ ei, const float* __restrict__ esh,
    const int* __restrict__ ROWP, int* __restrict__ CNT2,
    int* __restrict__ SLOT, int* __restrict__ DSTP, float* __restrict__ SHP)
{
    int e = blockIdx.x * 256 + threadIdx.x;
    if (e >= N_EDGES) return;
    int src = ei[e];
    int pos = atomicAdd(&CNT2[src], 1);
    int slot = ROWP[src] + pos;
    SLOT[e] = slot;
    DSTP[slot] = ei[N_EDGES + e];
    *(float4*)(SHP + (size_t)slot*4) = *(const float4*)(esh + (size_t)e*4);
}

// ---------------------------------------------------------------------------
// K3: edge MLP via fp16 MFMA, barrier-free wave-per-16-edges (R9-verified),
// writing WP at SLOT[e] (512-B full-line scattered stores). TP-packed layout:
//   WP[slot][j]    = (w0[j], w1[j])  j=0..63
//   WP[slot][64+u] = (w2[u], w3[u]) u<32 | (w4[u-32], w3[u-32]) u>=32
// ---------------------------------------------------------------------------
__global__ __launch_bounds__(256, 4) void k_edge_mlp(
    const float* __restrict__ eat, const int* __restrict__ SLOT,
    const _Float16* __restrict__ gA1, const _Float16* __restrict__ gA2,
    const _Float16* __restrict__ gA3,
    uint* __restrict__ WP)
{
    __shared__ _Float16 h1b[64*72];     //  9 KB (wave-private rows)
    __shared__ _Float16 h2b[64*72];     //  9 KB

    const int tid = threadIdx.x;
    const int lane = tid & 63, wv = tid >> 6;
    const int q = lane >> 4, col = lane & 15;
    const int erow = wv*16 + col;
    const int ecol = blockIdx.x*64 + erow;   // grid exact: no tail

    const float IS8 = 0.35355339059327373f;  // 1/sqrt(8)

    f16x8 b1;
#pragma unroll
    for (int j = 0; j < 8; ++j) b1[j] = (_Float16)0.f;
    if (q == 0) {
        float4 v0 = *(const float4*)(eat + (size_t)ecol*8);
        float4 v1 = *(const float4*)(eat + (size_t)ecol*8 + 4);
        b1[0]=(_Float16)v0.x; b1[1]=(_Float16)v0.y; b1[2]=(_Float16)v0.z; b1[3]=(_Float16)v0.w;
        b1[4]=(_Float16)v1.x; b1[5]=(_Float16)v1.y; b1[6]=(_Float16)v1.z; b1[7]=(_Float16)v1.w;
    }
#pragma unroll
    for (int nt = 0; nt < 4; ++nt) {
        f32x4 acc = {0.f,0.f,0.f,0.f};
        f16x8 a = *(const f16x8*)&gA1[(nt*64 + lane)*8];
        acc = __builtin_amdgcn_mfma_f32_16x16x32_f16(a, b1, acc, 0, 0, 0);
        f16x4 p;
#pragma unroll
        for (int r = 0; r < 4; ++r) p[r] = (_Float16)silu_f(acc[r]*IS8);
        *(f16x4*)&h1b[erow*72 + nt*16 + q*4] = p;
    }
#pragma unroll
    for (int nt = 0; nt < 4; ++nt) {
        f32x4 acc = {0.f,0.f,0.f,0.f};
#pragma unroll
        for (int ks = 0; ks < 2; ++ks) {
            f16x8 a = *(const f16x8*)&gA2[((ks*4+nt)*64 + lane)*8];
            f16x8 b = *(const f16x8*)&h1b[erow*72 + ks*32 + q*8];
            acc = __builtin_amdgcn_mfma_f32_16x16x32_f16(a, b, acc, 0, 0, 0);
        }
        f16x4 p;
#pragma unroll
        for (int r = 0; r < 4; ++r) p[r] = (_Float16)silu_f(acc[r]*0.125f);
        *(f16x4*)&h2b[erow*72 + nt*16 + q*4] = p;
    }
    int slot = SLOT[ecol];
    uint* wpE = WP + (size_t)slot*128;
    auto tileAcc = [&](int nt) -> f32x4 {
        f32x4 acc = {0.f,0.f,0.f,0.f};
#pragma unroll
        for (int ks = 0; ks < 2; ++ks) {
            f16x8 a = *(const f16x8*)&gA3[((ks*14+nt)*64 + lane)*8];
            f16x8 b = *(const f16x8*)&h2b[erow*72 + ks*32 + q*8];
            acc = __builtin_amdgcn_mfma_f32_16x16x32_f16(a, b, acc, 0, 0, 0);
        }
        return acc;
    };
    auto packStore = [&](f32x4 A, f32x4 B, int baseIdx) {
        uint d[4];
#pragma unroll
        for (int r = 0; r < 4; ++r) {
            __half2 h = __floats2half2_rn(A[r]*0.125f, B[r]*0.125f);
            d[r] = *(uint*)&h;
        }
        *(uint4*)&wpE[baseIdx + q*4] = make_uint4(d[0], d[1], d[2], d[3]);
    };
    f32x4 t10 = tileAcc(10);
    f32x4 t11 = tileAcc(11);
    packStore(tileAcc(0),  tileAcc(4),  0);
    packStore(tileAcc(1),  tileAcc(5),  16);
    packStore(tileAcc(2),  tileAcc(6),  32);
    packStore(tileAcc(3),  tileAcc(7),  48);
    packStore(tileAcc(8),  t10,         64);
    packStore(tileAcc(9),  t11,         80);
    packStore(tileAcc(12), t10,         96);
    packStore(tileAcc(13), t11,        112);
}

// ---------------------------------------------------------------------------
// K4: two waves per node; ALL per-edge streams sequential in slot order
// (WP rows, SHP, preloaded DSTP) — only the XS gather is random. No LIST,
// no e-shfl, minimal address math.
// ---------------------------------------------------------------------------
struct Pref { float4 sh, vv; float sd; uint wa, wb; };

__device__ __forceinline__ void preload(
    Pref& P, int slot, int dst,
    const float* __restrict__ SHP, const uint* __restrict__ WP,
    const float* __restrict__ XS, int lane, int u_)
{
    P.sh = *(const float4*)(SHP + (size_t)slot*4);
    const uint* wp = WP + (size_t)slot*128;
    P.wa = wp[lane];
    P.wb = wp[64 + lane];
    const float* xd = XS + (size_t)dst*192;
    P.sd = xd[lane];
    P.vv = *(const float4*)(xd + 64 + u_*4);
}

__global__ __launch_bounds__(256) void k_aggregate(
    const uint* __restrict__ WP, const float* __restrict__ SHP,
    const int* __restrict__ DSTP, const float* __restrict__ XS,
    const float* __restrict__ SC, const int* __restrict__ CNT,
    const int* __restrict__ ROWP,
    const float* __restrict__ W2_0, const float* __restrict__ W2_1,
    const float* __restrict__ g0, const float* __restrict__ g1,
    float* __restrict__ out)
{
    __shared__ float aSb[2][2][96];     // [node2][half][row]
    __shared__ float aVb[2][2][392];    // [node2][half][c*130 + row]
    int tid = threadIdx.x;
    int lane = tid & 63, wv = tid >> 6;
    int n2 = wv >> 1, half = wv & 1;
    int n = blockIdx.x*2 + n2;          // grid exact
    int u_ = lane & 31;
    bool lo = lane < 32;

    int cnt; { int c = CNT[n]; cnt = c > 64 ? 64 : c; }
    int base = ROWP[n];

    int dst_l = 0;
    if (lane < cnt) dst_l = DSTP[base + lane];   // coalesced

    float accM0=0, aV0x=0, aV0y=0, aV0z=0, accM1=0, a12x=0, a12y=0, a12z=0;

    Pref P;
    int i = half;
    if (i < cnt) preload(P, base+i, __shfl(dst_l,i), SHP, WP, XS, lane, u_);
#pragma unroll 1
    for (; i < cnt; i += 2) {
        Pref cur = P;
        int nx = i + 2;
        if (nx < cnt) preload(P, base+nx, __shfl(dst_l,nx), SHP, WP, XS, lane, u_);
        float2 f01 = __half22float2(*(const __half2*)&cur.wa);  // (w0, w1)
        float2 fAB = __half22float2(*(const __half2*)&cur.wb);  // (w2|w4, w3)
        accM0 += f01.x*cur.sd*cur.sh.x;                          // m0
        float t1 = f01.y*cur.sd;                                 // mv0
        aV0x += t1*cur.sh.y; aV0y += t1*cur.sh.z; aV0z += t1*cur.sh.w;
        if (lo) {
            accM1 += fAB.y*(cur.vv.x*cur.sh.y + cur.vv.y*cur.sh.z + cur.vv.z*cur.sh.w); // m1
            a12x += fAB.x*cur.vv.x*cur.sh.x;                     // mv1
            a12y += fAB.x*cur.vv.y*cur.sh.x;
            a12z += fAB.x*cur.vv.z*cur.sh.x;
        } else {                                                 // mv2: w4*cross(vd,sh1)
            a12x += fAB.x*(cur.vv.y*cur.sh.w - cur.vv.z*cur.sh.z);
            a12y += fAB.x*(cur.vv.z*cur.sh.y - cur.vv.x*cur.sh.w);
            a12z += fAB.x*(cur.vv.x*cur.sh.z - cur.vv.y*cur.sh.y);
        }
    }

    const float SEG = 0.25f;                    // 1/sqrt(16)
    const float IS3 = 0.5773502691896258f;      // 1/sqrt(3)
    const float IS2 = 0.7071067811865476f;      // 1/sqrt(2)
    aSb[n2][half][lane] = accM0 * SEG;
    aVb[n2][half][0*130 + lane] = aV0x * SEG;
    aVb[n2][half][1*130 + lane] = aV0y * SEG;
    aVb[n2][half][2*130 + lane] = aV0z * SEG;
    if (lo) {
        aSb[n2][half][64 + u_] = accM1 * SEG * IS3;
        aVb[n2][half][0*130 + 64 + u_] = a12x * SEG;
        aVb[n2][half][1*130 + 64 + u_] = a12y * SEG;
        aVb[n2][half][2*130 + 64 + u_] = a12z * SEG;
    } else {
        aVb[n2][half][0*130 + 96 + u_] = a12x * SEG * IS2;
        aVb[n2][half][1*130 + 96 + u_] = a12y * SEG * IS2;
        aVb[n2][half][2*130 + 96 + u_] = a12z * SEG * IS2;
    }
    __syncthreads();

    if (half == 0) {
        aSb[n2][0][lane] += aSb[n2][1][lane];
        if (lo) aSb[n2][0][64 + u_] += aSb[n2][1][64 + u_];

        float o0=0,o1=0,o2=0,o3=0;
#pragma unroll 4
        for (int k = 0; k < 96; k += 4) {
            o0 += aSb[n2][0][k+0] * W2_0[(k+0)*64 + lane];
            o1 += aSb[n2][0][k+1] * W2_0[(k+1)*64 + lane];
            o2 += aSb[n2][0][k+2] * W2_0[(k+2)*64 + lane];
            o3 += aSb[n2][0][k+3] * W2_0[(k+3)*64 + lane];
        }
        float os = (o0+o1)+(o2+o3);
        const float IS96 = 0.10206207261596575f;  // 1/sqrt(96)
        os = os*IS96 + SC[n*192 + lane];

        float r = os*os;
#pragma unroll
        for (int off = 32; off > 0; off >>= 1) r += __shfl_xor(r, off);
        float rms_s = sqrtf(r*(1.0f/64.0f) + EPS_F);
        out[(size_t)n*160 + lane] = os / rms_s * g0[lane];
    } else {
        for (int idx = lane; idx < 392; idx += 64)
            aVb[n2][0][idx] += aVb[n2][1][idx];

        int coff = lo ? 0 : 2*130;
        float p0=0,p1=0,q0=0,q1=0;
#pragma unroll 4
        for (int u = 0; u < 128; u += 2) {
            float wv0 = W2_1[(u+0)*32 + u_];
            float wv1 = W2_1[(u+1)*32 + u_];
            p0 += aVb[n2][0][coff + u+0]*wv0;  q0 += aVb[n2][0][130 + u+0]*wv0;
            p1 += aVb[n2][0][coff + u+1]*wv1;  q1 += aVb[n2][0][130 + u+1]*wv1;
        }
        float ov0 = p0+p1, ov1 = q0+q1;
        const float IS128 = 0.08838834764831845f; // 1/sqrt(128)
        float4 scv = *(const float4*)(SC + n*192 + 64 + u_*4);
        float x0 = ov0*IS128 + (lo ? scv.x : scv.z);
        float x1 = ov1*IS128 + scv.y;

        float rv = lo ? (x0*x0 + x1*x1) : (x0*x0);
#pragma unroll
        for (int off = 32; off > 0; off >>= 1) rv += __shfl_xor(rv, off);
        float rms_v = sqrtf(rv*(1.0f/32.0f) + EPS_F);

        float* orow = out + (size_t)n*160;
        float gv = g1[u_] / rms_v;
        if (lo) {
            orow[64 + u_*3 + 0] = x0 * gv;
            orow[64 + u_*3 + 1] = x1 * gv;
        } else {
            orow[64 + u_*3 + 2] = x0 * gv;
        }
    }
}

// ---------------------------------------------------------------------------
extern "C" void kernel_launch(void* const* d_in, const int* in_sizes, int n_in,
                              void* d_out, int out_size, void* d_ws, size_t ws_size,
                              hipStream_t stream)
{
    const float* nh   = (const float*)d_in[0];
    const int*   ei   = (const int*)  d_in[1];
    const float* esh  = (const float*)d_in[2];
    const float* eat  = (const float*)d_in[3];
    const float* W1_0 = (const float*)d_in[4];
    const float* W1_1 = (const float*)d_in[5];
    const float* Wfc1 = (const float*)d_in[6];
    const float* Wfc2 = (const float*)d_in[7];
    const float* Wfc3 = (const float*)d_in[8];
    const float* W2_0 = (const float*)d_in[9];
    const float* W2_1 = (const float*)d_in[10];
    const float* Wsc0 = (const float*)d_in[11];
    const float* Wsc1 = (const float*)d_in[12];
    const float* g0   = (const float*)d_in[13];
    const float* g1   = (const float*)d_in[14];
    float* out = (float*)d_out;

    // workspace layout — ~253 MB (< 256 MiB)
    char* base = (char*)d_ws;
    float*    XS   = (float*)base;                             // N*192 f32   19.2 MB
    float*    SC   = XS + (size_t)N_NODES*192;                 // N*192 f32   19.2 MB
    uint*     WP   = (uint*)(SC + (size_t)N_NODES*192);        // E*128 u32  204.8 MB
    float*    SHP  = (float*)(WP + (size_t)N_EDGES*128);       // E*4 f32      6.4 MB
    _Float16* gA1  = (_Float16*)(SHP + (size_t)N_EDGES*4);     // 2048 f16
    _Float16* gA2  = gA1 + 2048;                               // 4096 f16
    _Float16* gA3  = gA2 + 4096;                               // 14336 f16
    int*      CNT  = (int*)(gA3 + 14336);                      // N int
    int*      CNT2 = CNT + N_NODES;                            // N int
    int*      ROWP = CNT2 + N_NODES;                           // N int
    int*      SLOT = ROWP + N_NODES;                           // E int        1.6 MB
    int*      DSTP = SLOT + N_EDGES;                           // E int        1.6 MB

    hipMemsetAsync(CNT, 0, 2*N_NODES*sizeof(int), stream);     // CNT + CNT2
    k_prepack <<<10, 256, 0, stream>>>(Wfc1, Wfc2, Wfc3, gA1, gA2, gA3);
    k_count   <<<(N_EDGES+255)/256, 256, 0, stream>>>(ei, CNT);
    k_scan    <<<1, 256, 0, stream>>>(CNT, ROWP);
    k_fill    <<<(N_EDGES+255)/256, 256, 0, stream>>>(ei, esh, ROWP, CNT2,
                                                      SLOT, DSTP, SHP);
    k_node_pre<<<(N_NODES+3)/4, 256, 0, stream>>>(nh, W1_0, W1_1, Wsc0, Wsc1, XS, SC);
    k_edge_mlp<<<N_EDGES/64, 256, 0, stream>>>(eat, SLOT, gA1, gA2, gA3, WP);
    k_aggregate<<<N_NODES/2, 256, 0, stream>>>(WP, SHP, DSTP, XS, SC, CNT, ROWP,
                                               W2_0, W2_1, g0, g1, out);
}

// Round 11
// 375.769 us; speedup vs baseline: 1.1828x; 1.1828x over previous
//
#include <hip/hip_runtime.h>
#include <hip/hip_fp16.h>

#define N_NODES 25000
#define N_EDGES 400000
#define EPS_F 1e-5f

typedef _Float16 f16x8 __attribute__((ext_vector_type(8)));
typedef _Float16 f16x4 __attribute__((ext_vector_type(4)));
typedef float    f32x4 __attribute__((ext_vector_type(4)));
typedef unsigned int uint;

__device__ __forceinline__ float silu_f(float x) {
    return x / (1.0f + __expf(-x));
}

// ---------------------------------------------------------------------------
// K0: pre-pack Wfc1/2/3 into MFMA A-fragment order (R7/R8-verified layout).
// ---------------------------------------------------------------------------
__global__ __launch_bounds__(256) void k_prepack(
    const float* __restrict__ Wfc1, const float* __restrict__ Wfc2,
    const float* __restrict__ Wfc3,
    _Float16* __restrict__ gA1, _Float16* __restrict__ gA2,
    _Float16* __restrict__ gA3)
{
    int t = blockIdx.x * 256 + threadIdx.x;
    int L = t & 63, q = L >> 4, cc = L & 15;
    if (t < 256) {
        int nt = t >> 6;
        f16x8 p;
#pragma unroll
        for (int j = 0; j < 8; ++j)
            p[j] = (q == 0) ? (_Float16)Wfc1[j*64 + nt*16 + cc] : (_Float16)0.f;
        *(f16x8*)&gA1[t*8] = p;
    } else if (t < 768) {
        int tt = t - 256;
        int tile = tt >> 6, ks = tile >> 2, nt = tile & 3;
        int kb = ks*32 + q*8;
        f16x8 p;
#pragma unroll
        for (int j = 0; j < 8; ++j)
            p[j] = (_Float16)Wfc2[(kb+j)*64 + nt*16 + cc];
        *(f16x8*)&gA2[tt*8] = p;
    } else if (t < 2560) {
        int tt = t - 768;
        int tile = tt >> 6, ks = tile / 14, nt = tile - ks*14;
        int kb = ks*32 + q*8;
        f16x8 p;
#pragma unroll
        for (int j = 0; j < 8; ++j)
            p[j] = (_Float16)Wfc3[(kb+j)*224 + nt*16 + cc];
        *(f16x8*)&gA3[tt*8] = p;
    }
}

// ---------------------------------------------------------------------------
// K1: per-node linear transforms, WAVE-per-node (R7/R8-verified).
// XS/SC row: [0..63]=s, [64+v*4+c]=v (c<3, pad).
// ---------------------------------------------------------------------------
__global__ __launch_bounds__(256) void k_node_pre(
    const float* __restrict__ nh,
    const float* __restrict__ W1_0, const float* __restrict__ W1_1,
    const float* __restrict__ Wsc0, const float* __restrict__ Wsc1,
    float* __restrict__ XS, float* __restrict__ SC)
{
    int lane = threadIdx.x & 63, wv = threadIdx.x >> 6;
    int n = blockIdx.x*4 + wv;
    if (n >= N_NODES) return;
    int u_ = lane & 31;
    bool lo = lane < 32;
    const float* row = nh + n*160;

    float sval = row[lane];
    float vx = row[64 + u_*3 + 0];
    float vy = row[64 + u_*3 + 1];
    float vz = row[64 + u_*3 + 2];

    float as = 0.f, bs = 0.f;
#pragma unroll 4
    for (int k = 0; k < 64; ++k) {
        float sk = __shfl(sval, k);
        as += sk * W1_0[k*64 + lane];
        bs += sk * Wsc0[k*64 + lane];
    }
    float* xsrow = XS + n*192;
    float* scrow = SC + n*192;
    xsrow[lane] = as * 0.125f;
    scrow[lane] = bs * 0.125f;

    float selv = lo ? vx : vz;
    int srcbase = lane & 32;                   // hi lanes source vz from 32..63
    float aP=0.f, aQ=0.f, bP=0.f, bQ=0.f;
#pragma unroll 4
    for (int u = 0; u < 32; ++u) {
        float su = __shfl(selv, u | srcbase);
        float sy = __shfl(vy, u);
        float wa = W1_1[u*32 + u_];
        float wb = Wsc1[u*32 + u_];
        aP += su*wa; aQ += sy*wa;
        bP += su*wb; bQ += sy*wb;
    }
    const float is32 = 0.17677669529663687f;
    if (lo) {
        xsrow[64 + u_*4 + 0] = aP * is32;
        xsrow[64 + u_*4 + 1] = aQ * is32;
        scrow[64 + u_*4 + 0] = bP * is32;
        scrow[64 + u_*4 + 1] = bQ * is32;
    } else {
        xsrow[64 + u_*4 + 2] = aP * is32;
        scrow[64 + u_*4 + 2] = bP * is32;
    }
}

// ---------------------------------------------------------------------------
// K2: per-src edge lists. Only int atomics (400k).
// ---------------------------------------------------------------------------
__global__ __launch_bounds__(256) void k_build_lists(
    const int* __restrict__ ei, int* __restrict__ CNT, int* __restrict__ LIST)
{
    int e = blockIdx.x * 256 + threadIdx.x;
    if (e >= N_EDGES) return;
    int src = ei[e];
    int pos = atomicAdd(&CNT[src], 1);
    if (pos < 64) LIST[src*64 + pos] = e;
}

// ---------------------------------------------------------------------------
// K3: edge MLP via fp16 MFMA, barrier-free wave-per-16-edges (R9-verified).
// TP-packed WP layout (dwords), written at e (sequential full 512-B rows):
//   WP[e][j]    = (w0[j], w1[j])  j=0..63
//   WP[e][64+u] = (w2[u], w3[u]) u<32 | (w4[u-32], w3[u-32]) u>=32
// ---------------------------------------------------------------------------
__global__ __launch_bounds__(256, 4) void k_edge_mlp(
    const float* __restrict__ eat,
    const _Float16* __restrict__ gA1, const _Float16* __restrict__ gA2,
    const _Float16* __restrict__ gA3,
    uint* __restrict__ WP)
{
    __shared__ _Float16 h1b[64*72];     //  9 KB (wave-private rows)
    __shared__ _Float16 h2b[64*72];     //  9 KB

    const int tid = threadIdx.x;
    const int lane = tid & 63, wv = tid >> 6;
    const int q = lane >> 4, col = lane & 15;
    const int erow = wv*16 + col;
    const int ecol = blockIdx.x*64 + erow;   // grid exact: no tail

    const float IS8 = 0.35355339059327373f;  // 1/sqrt(8)

    f16x8 b1;
#pragma unroll
    for (int j = 0; j < 8; ++j) b1[j] = (_Float16)0.f;
    if (q == 0) {
        float4 v0 = *(const float4*)(eat + (size_t)ecol*8);
        float4 v1 = *(const float4*)(eat + (size_t)ecol*8 + 4);
        b1[0]=(_Float16)v0.x; b1[1]=(_Float16)v0.y; b1[2]=(_Float16)v0.z; b1[3]=(_Float16)v0.w;
        b1[4]=(_Float16)v1.x; b1[5]=(_Float16)v1.y; b1[6]=(_Float16)v1.z; b1[7]=(_Float16)v1.w;
    }
#pragma unroll
    for (int nt = 0; nt < 4; ++nt) {
        f32x4 acc = {0.f,0.f,0.f,0.f};
        f16x8 a = *(const f16x8*)&gA1[(nt*64 + lane)*8];
        acc = __builtin_amdgcn_mfma_f32_16x16x32_f16(a, b1, acc, 0, 0, 0);
        f16x4 p;
#pragma unroll
        for (int r = 0; r < 4; ++r) p[r] = (_Float16)silu_f(acc[r]*IS8);
        *(f16x4*)&h1b[erow*72 + nt*16 + q*4] = p;
    }
#pragma unroll
    for (int nt = 0; nt < 4; ++nt) {
        f32x4 acc = {0.f,0.f,0.f,0.f};
#pragma unroll
        for (int ks = 0; ks < 2; ++ks) {
            f16x8 a = *(const f16x8*)&gA2[((ks*4+nt)*64 + lane)*8];
            f16x8 b = *(const f16x8*)&h1b[erow*72 + ks*32 + q*8];
            acc = __builtin_amdgcn_mfma_f32_16x16x32_f16(a, b, acc, 0, 0, 0);
        }
        f16x4 p;
#pragma unroll
        for (int r = 0; r < 4; ++r) p[r] = (_Float16)silu_f(acc[r]*0.125f);
        *(f16x4*)&h2b[erow*72 + nt*16 + q*4] = p;
    }
    uint* wpE = WP + (size_t)ecol*128;
    auto tileAcc = [&](int nt) -> f32x4 {
        f32x4 acc = {0.f,0.f,0.f,0.f};
#pragma unroll
        for (int ks = 0; ks < 2; ++ks) {
            f16x8 a = *(const f16x8*)&gA3[((ks*14+nt)*64 + lane)*8];
            f16x8 b = *(const f16x8*)&h2b[erow*72 + ks*32 + q*8];
            acc = __builtin_amdgcn_mfma_f32_16x16x32_f16(a, b, acc, 0, 0, 0);
        }
        return acc;
    };
    auto packStore = [&](f32x4 A, f32x4 B, int baseIdx) {
        uint d[4];
#pragma unroll
        for (int r = 0; r < 4; ++r) {
            __half2 h = __floats2half2_rn(A[r]*0.125f, B[r]*0.125f);
            d[r] = *(uint*)&h;
        }
        *(uint4*)&wpE[baseIdx + q*4] = make_uint4(d[0], d[1], d[2], d[3]);
    };
    f32x4 t10 = tileAcc(10);
    f32x4 t11 = tileAcc(11);
    packStore(tileAcc(0),  tileAcc(4),  0);
    packStore(tileAcc(1),  tileAcc(5),  16);
    packStore(tileAcc(2),  tileAcc(6),  32);
    packStore(tileAcc(3),  tileAcc(7),  48);
    packStore(tileAcc(8),  t10,         64);
    packStore(tileAcc(9),  t11,         80);
    packStore(tileAcc(12), t10,         96);
    packStore(tileAcc(13), t11,        112);
}

// ---------------------------------------------------------------------------
// K4: FOUR waves per node (quarter of the edges each; serial depth ~4).
// R9-verified math; 100k waves total to fill the 37% VALU idle the 2-wave
// version left (R9/R10: VALUBusy 60-63%, occupancy 75% — latency bubbles).
// ---------------------------------------------------------------------------
struct Pref { float4 sh, vv; float sd; uint wa, wb; };

__device__ __forceinline__ void preload(
    Pref& P, int e, int dst,
    const float* __restrict__ esh, const uint* __restrict__ WP,
    const float* __restrict__ XS, int lane, int u_)
{
    P.sh = *(const float4*)(esh + (size_t)e*4);
    const uint* wp = WP + (size_t)e*128;
    P.wa = wp[lane];
    P.wb = wp[64 + lane];
    const float* xd = XS + (size_t)dst*192;
    P.sd = xd[lane];
    P.vv = *(const float4*)(xd + 64 + u_*4);
}

__global__ __launch_bounds__(256) void k_aggregate(
    const int* __restrict__ ei, const float* __restrict__ esh,
    const uint* __restrict__ WP, const float* __restrict__ XS,
    const float* __restrict__ SC, const int* __restrict__ CNT,
    const int* __restrict__ LIST,
    const float* __restrict__ W2_0, const float* __restrict__ W2_1,
    const float* __restrict__ g0, const float* __restrict__ g1,
    float* __restrict__ out)
{
    __shared__ float aSb[4][96];        // [quarter][row]
    __shared__ float aVb[4][392];       // [quarter][c*130 + row]
    int tid = threadIdx.x;
    int lane = tid & 63, wv = tid >> 6; // wv = quarter 0..3
    int n = blockIdx.x;                 // one node per block (grid exact)
    int u_ = lane & 31;
    bool lo = lane < 32;

    int cnt; { int c = CNT[n]; cnt = c > 64 ? 64 : c; }
    const int* edst = ei + N_EDGES;

    int e_l = 0, dst_l = 0;
    if (cnt > 0) {
        int li = lane < cnt ? lane : cnt - 1;
        e_l = LIST[n*64 + li];
        dst_l = edst[e_l];
    }

    float accM0=0, aV0x=0, aV0y=0, aV0z=0, accM1=0, a12x=0, a12y=0, a12z=0;

    Pref P;
    int i = wv;
    if (i < cnt) preload(P, __shfl(e_l,i), __shfl(dst_l,i), esh, WP, XS, lane, u_);
#pragma unroll 1
    for (; i < cnt; i += 4) {
        Pref cur = P;
        int nx = i + 4;
        if (nx < cnt) preload(P, __shfl(e_l,nx), __shfl(dst_l,nx), esh, WP, XS, lane, u_);
        float2 f01 = __half22float2(*(const __half2*)&cur.wa);  // (w0, w1)
        float2 fAB = __half22float2(*(const __half2*)&cur.wb);  // (w2|w4, w3)
        accM0 += f01.x*cur.sd*cur.sh.x;                          // m0
        float t1 = f01.y*cur.sd;                                 // mv0
        aV0x += t1*cur.sh.y; aV0y += t1*cur.sh.z; aV0z += t1*cur.sh.w;
        if (lo) {
            accM1 += fAB.y*(cur.vv.x*cur.sh.y + cur.vv.y*cur.sh.z + cur.vv.z*cur.sh.w); // m1
            a12x += fAB.x*cur.vv.x*cur.sh.x;                     // mv1
            a12y += fAB.x*cur.vv.y*cur.sh.x;
            a12z += fAB.x*cur.vv.z*cur.sh.x;
        } else {                                                 // mv2: w4*cross(vd,sh1)
            a12x += fAB.x*(cur.vv.y*cur.sh.w - cur.vv.z*cur.sh.z);
            a12y += fAB.x*(cur.vv.z*cur.sh.y - cur.vv.x*cur.sh.w);
            a12z += fAB.x*(cur.vv.x*cur.sh.z - cur.vv.y*cur.sh.y);
        }
    }

    const float SEG = 0.25f;                    // 1/sqrt(16)
    const float IS3 = 0.5773502691896258f;      // 1/sqrt(3)
    const float IS2 = 0.7071067811865476f;      // 1/sqrt(2)
    aSb[wv][lane] = accM0 * SEG;
    aVb[wv][0*130 + lane] = aV0x * SEG;
    aVb[wv][1*130 + lane] = aV0y * SEG;
    aVb[wv][2*130 + lane] = aV0z * SEG;
    if (lo) {
        aSb[wv][64 + u_] = accM1 * SEG * IS3;
        aVb[wv][0*130 + 64 + u_] = a12x * SEG;
        aVb[wv][1*130 + 64 + u_] = a12y * SEG;
        aVb[wv][2*130 + 64 + u_] = a12z * SEG;
    } else {
        aVb[wv][0*130 + 96 + u_] = a12x * SEG * IS2;
        aVb[wv][1*130 + 96 + u_] = a12y * SEG * IS2;
        aVb[wv][2*130 + 96 + u_] = a12z * SEG * IS2;
    }
    __syncthreads();

    if (wv == 0) {
        // combine scalar partials
        aSb[0][lane] += aSb[1][lane] + aSb[2][lane] + aSb[3][lane];
        if (lo) aSb[0][64 + u_] += aSb[1][64 + u_] + aSb[2][64 + u_] + aSb[3][64 + u_];

        // out_s = ns @ W2_0 / sqrt(96) + sc_s
        float o0=0,o1=0,o2=0,o3=0;
#pragma unroll 4
        for (int k = 0; k < 96; k += 4) {
            o0 += aSb[0][k+0] * W2_0[(k+0)*64 + lane];
            o1 += aSb[0][k+1] * W2_0[(k+1)*64 + lane];
            o2 += aSb[0][k+2] * W2_0[(k+2)*64 + lane];
            o3 += aSb[0][k+3] * W2_0[(k+3)*64 + lane];
        }
        float os = (o0+o1)+(o2+o3);
        const float IS96 = 0.10206207261596575f;  // 1/sqrt(96)
        os = os*IS96 + SC[n*192 + lane];

        float r = os*os;
#pragma unroll
        for (int off = 32; off > 0; off >>= 1) r += __shfl_xor(r, off);
        float rms_s = sqrtf(r*(1.0f/64.0f) + EPS_F);
        out[(size_t)n*160 + lane] = os / rms_s * g0[lane];
    } else if (wv == 1) {
        // combine vector partials
        for (int idx = lane; idx < 392; idx += 64)
            aVb[0][idx] += aVb[1][idx] + aVb[2][idx] + aVb[3][idx];

        // out_v[v][c] = sum_u nv[u][c] * W2_1[u][v] / sqrt(128) + sc_v
        int coff = lo ? 0 : 2*130;
        float p0=0,p1=0,q0=0,q1=0;
#pragma unroll 4
        for (int u = 0; u < 128; u += 2) {
            float wv0 = W2_1[(u+0)*32 + u_];
            float wv1 = W2_1[(u+1)*32 + u_];
            p0 += aVb[0][coff + u+0]*wv0;  q0 += aVb[0][130 + u+0]*wv0;
            p1 += aVb[0][coff + u+1]*wv1;  q1 += aVb[0][130 + u+1]*wv1;
        }
        float ov0 = p0+p1, ov1 = q0+q1;
        const float IS128 = 0.08838834764831845f; // 1/sqrt(128)
        float4 scv = *(const float4*)(SC + n*192 + 64 + u_*4);
        float x0 = ov0*IS128 + (lo ? scv.x : scv.z);
        float x1 = ov1*IS128 + scv.y;

        float rv = lo ? (x0*x0 + x1*x1) : (x0*x0);
#pragma unroll
        for (int off = 32; off > 0; off >>= 1) rv += __shfl_xor(rv, off);
        float rms_v = sqrtf(rv*(1.0f/32.0f) + EPS_F);

        float* orow = out + (size_t)n*160;
        float gv = g1[u_] / rms_v;
        if (lo) {
            orow[64 + u_*3 + 0] = x0 * gv;
            orow[64 + u_*3 + 1] = x1 * gv;
        } else {
            orow[64 + u_*3 + 2] = x0 * gv;
        }
    }
}

// ---------------------------------------------------------------------------
extern "C" void kernel_launch(void* const* d_in, const int* in_sizes, int n_in,
                              void* d_out, int out_size, void* d_ws, size_t ws_size,
                              hipStream_t stream)
{
    const float* nh   = (const float*)d_in[0];
    const int*   ei   = (const int*)  d_in[1];
    const float* esh  = (const float*)d_in[2];
    const float* eat  = (const float*)d_in[3];
    const float* W1_0 = (const float*)d_in[4];
    const float* W1_1 = (const float*)d_in[5];
    const float* Wfc1 = (const float*)d_in[6];
    const float* Wfc2 = (const float*)d_in[7];
    const float* Wfc3 = (const float*)d_in[8];
    const float* W2_0 = (const float*)d_in[9];
    const float* W2_1 = (const float*)d_in[10];
    const float* Wsc0 = (const float*)d_in[11];
    const float* Wsc1 = (const float*)d_in[12];
    const float* g0   = (const float*)d_in[13];
    const float* g1   = (const float*)d_in[14];
    float* out = (float*)d_out;

    // workspace layout — ~250 MB
    char* base = (char*)d_ws;
    float*    XS   = (float*)base;                             // N*192 f32   19.2 MB
    float*    SC   = XS + (size_t)N_NODES*192;                 // N*192 f32   19.2 MB
    uint*     WP   = (uint*)(SC + (size_t)N_NODES*192);        // E*128 u32  204.8 MB
    _Float16* gA1  = (_Float16*)(WP + (size_t)N_EDGES*128);    // 2048 f16
    _Float16* gA2  = gA1 + 2048;                               // 4096 f16
    _Float16* gA3  = gA2 + 4096;                               // 14336 f16
    int*      CNT  = (int*)(gA3 + 14336);                      // N int
    int*      LIST = CNT + N_NODES;                            // N*64 int     6.4 MB

    hipMemsetAsync(CNT, 0, N_NODES*sizeof(int), stream);
    k_prepack   <<<10, 256, 0, stream>>>(Wfc1, Wfc2, Wfc3, gA1, gA2, gA3);
    k_node_pre  <<<(N_NODES+3)/4, 256, 0, stream>>>(nh, W1_0, W1_1, Wsc0, Wsc1, XS, SC);
    k_build_lists<<<(N_EDGES+255)/256, 256, 0, stream>>>(ei, CNT, LIST);
    k_edge_mlp  <<<N_EDGES/64, 256, 0, stream>>>(eat, gA1, gA2, gA3, WP);
    k_aggregate <<<N_NODES, 256, 0, stream>>>(ei, esh, WP, XS, SC, CNT, LIST,
                                              W2_0, W2_1, g0, g1, out);
}